// Round 1
// baseline (831.839 us; speedup 1.0000x reference)
//
#include <hip/hip_runtime.h>

#define KVOL 27
#define CIN  32
#define COUT 64

// ---------------------------------------------------------------------------
// out[r][c] = bias[c]   (carries the +bias term; scatter kernel adds on top)
// ---------------------------------------------------------------------------
__global__ __launch_bounds__(256) void init_out_kernel(float* __restrict__ out,
                                                       const float* __restrict__ bias,
                                                       int total4) {
  // total4 = N * (COUT/4); each thread writes float4. Grid stride is a
  // multiple of 16 float4 (=one row), so (i & 15) is loop-invariant.
  int i0 = blockIdx.x * 256 + threadIdx.x;
  float4 b = ((const float4*)bias)[i0 & 15];
  for (int i = i0; i < total4; i += gridDim.x * 256) {
    ((float4*)out)[i] = b;
  }
}

// ---------------------------------------------------------------------------
// One wave per (k, m) pair. lane = output channel (COUT == wave size == 64).
// Weights for offset k live in 32 VGPRs/lane. Feature row read as 8 broadcast
// float4 loads (single 128B line, L1-cached). 32 FMA + 1 atomicAdd per lane.
// ---------------------------------------------------------------------------
__global__ __launch_bounds__(256) void scatter_conv_kernel(
    const float* __restrict__ feat,   // [N][CIN]
    const int2*  __restrict__ kmap,   // [KVOL][M] pairs (in_idx, out_idx)
    const float* __restrict__ kern,   // [KVOL][CIN][COUT]
    float*       __restrict__ out,    // [N][COUT]
    int M) {
  const int k    = blockIdx.y;
  const int lane = threadIdx.x & 63;
  const int wave = threadIdx.x >> 6;

  // Per-lane weight column: w[i] = kern[k][i][lane]  (coalesced: 64 lanes x 4B)
  float w[CIN];
  const float* wk = kern + (size_t)k * CIN * COUT + lane;
#pragma unroll
  for (int i = 0; i < CIN; ++i) w[i] = wk[i * COUT];

  const int2* km = kmap + (size_t)k * M;
  const int nwaves = gridDim.x * 4;  // 4 waves per 256-thread block

  for (int m = blockIdx.x * 4 + wave; m < M; m += nwaves) {
    int2 pr = km[m];                 // same address across wave -> broadcast
    const float4* frow = (const float4*)(feat + (size_t)pr.x * CIN);
    float acc = 0.f;
#pragma unroll
    for (int j = 0; j < 8; ++j) {
      float4 v = frow[j];            // broadcast load, one 128B line per pair
      acc = fmaf(v.x, w[4 * j + 0], acc);
      acc = fmaf(v.y, w[4 * j + 1], acc);
      acc = fmaf(v.z, w[4 * j + 2], acc);
      acc = fmaf(v.w, w[4 * j + 3], acc);
    }
    atomicAdd(out + (size_t)pr.y * COUT + lane, acc);
  }
}

extern "C" void kernel_launch(void* const* d_in, const int* in_sizes, int n_in,
                              void* d_out, int out_size, void* d_ws, size_t ws_size,
                              hipStream_t stream) {
  const float* feat = (const float*)d_in[0];   // [N][CIN]
  // d_in[1] input_coord, d_in[2] input_cmap: unused by the reference math
  const int2*  kmap = (const int2*)d_in[3];    // [K][M][2]
  const float* kern = (const float*)d_in[4];   // [K][CIN][COUT]
  const float* bias = (const float*)d_in[5];   // [COUT]
  float* out = (float*)d_out;

  const int N = in_sizes[0] / CIN;
  const int M = in_sizes[3] / (2 * KVOL);

  // 1) out = bias (broadcast per row)
  int total4 = N * (COUT / 4);
  int initBlocks = 2048;
  hipLaunchKernelGGL(init_out_kernel, dim3(initBlocks), dim3(256), 0, stream,
                     out, bias, total4);

  // 2) scatter-accumulate all K*M pairs
  dim3 grid(128, KVOL);   // 128 blocks x 4 waves = 512 waves per offset
  hipLaunchKernelGGL(scatter_conv_kernel, grid, dim3(256), 0, stream,
                     feat, kmap, kern, out, M);
}